// Round 9
// baseline (428.603 us; speedup 1.0000x reference)
//
#include <hip/hip_runtime.h>

// Neurcomp / SIREN MLP inference — round 9: r8 transposed structure +
// tighter split numerics. r8 failed absmax by 1% (3.23e-3 vs 3.20e-3):
// the SIREN stack amplifies ~1e-6 rounding perturbations ~1e3x at the
// worst point, so the 3-term truncation split sat on a knife-edge.
// Fixes: (1) RNE rounding for BOTH hi and lo bf16 splits (acts+weights);
// (2) 4th MFMA term (w_lo x act_lo) — dropped term eliminated. Error
// budget ~6x smaller than r8 -> back at the 1-2 ulp floor.
// Layouts (verified): A[m=lane&15][k=(lane>>4)*8+j],
// B[k=(lane>>4)*8+j][n=lane&15], C/D col=lane&15 row=(lane>>4)*4+reg.

typedef unsigned int u32;
typedef short s8v __attribute__((ext_vector_type(8)));   // 8 bf16 (bits)
typedef float f4v __attribute__((ext_vector_type(4)));
typedef u32   u4v __attribute__((ext_vector_type(4)));
typedef u32   u2v __attribute__((ext_vector_type(2)));

constexpr float OMEGA = 30.0f;
constexpr int HID = 128, NRES = 7, BT = 64;
constexpr int RSTR = 136;               // u16 per plane row (17 x 16B)
constexpr int FRAG_ELEMS = 14 * 16384;  // bf16 elems per hi/lo ws array

__device__ __forceinline__ float sin_om(float z) {
    float r = z * (OMEGA * 0.15915494309189535f);
    r = r - floorf(r);
    return __builtin_amdgcn_sinf(r);
}

__device__ __forceinline__ f4v mfma16(s8v a, s8v b, f4v c) {
    return __builtin_amdgcn_mfma_f32_16x16x32_bf16(a, b, c, 0, 0, 0);
}

// RNE-round fp32 bits to bf16 (result in top 16 of returned word)
__device__ __forceinline__ u32 rne(u32 b) {
    return b + 0x7FFFu + ((b >> 16) & 1u);
}

// pack 4 consecutive-feature fp32 values into hi/lo bf16 planes, one
// ds_write_b64 each. hi = RNE(v); lo = RNE(v - hi).
__device__ __forceinline__ void plane_store4(unsigned short* ph,
                                             unsigned short* pl,
                                             int a, f4v v) {
    u32 b0 = __builtin_bit_cast(u32, v.x), b1 = __builtin_bit_cast(u32, v.y);
    u32 b2 = __builtin_bit_cast(u32, v.z), b3 = __builtin_bit_cast(u32, v.w);
    u32 r0 = rne(b0), r1 = rne(b1), r2 = rne(b2), r3 = rne(b3);
    u2v hv;
    hv.x = __builtin_amdgcn_perm(r1, r0, 0x07060302u);  // [r0.hi16 | r1.hi16]
    hv.y = __builtin_amdgcn_perm(r3, r2, 0x07060302u);
    float l0 = v.x - __builtin_bit_cast(float, r0 & 0xffff0000u);
    float l1 = v.y - __builtin_bit_cast(float, r1 & 0xffff0000u);
    float l2 = v.z - __builtin_bit_cast(float, r2 & 0xffff0000u);
    float l3 = v.w - __builtin_bit_cast(float, r3 & 0xffff0000u);
    u32 c0 = rne(__builtin_bit_cast(u32, l0));
    u32 c1 = rne(__builtin_bit_cast(u32, l1));
    u32 c2 = rne(__builtin_bit_cast(u32, l2));
    u32 c3 = rne(__builtin_bit_cast(u32, l3));
    u2v lv;
    lv.x = __builtin_amdgcn_perm(c1, c0, 0x07060302u);
    lv.y = __builtin_amdgcn_perm(c3, c2, 0x07060302u);
    *reinterpret_cast<u2v*>(ph + a) = hv;
    *reinterpret_cast<u2v*>(pl + a) = lv;
}

// ---- repetition lists ----
#define LMT8(M) M(0) M(1) M(2) M(3) M(4) M(5) M(6) M(7)
#define LAF8(M) M(0,0) M(0,1) M(0,2) M(0,3) M(1,0) M(1,1) M(1,2) M(1,3)
#define LH64(M) \
  M(0,0,0) M(0,0,1) M(0,0,2) M(0,0,3) M(0,1,0) M(0,1,1) M(0,1,2) M(0,1,3) \
  M(0,2,0) M(0,2,1) M(0,2,2) M(0,2,3) M(0,3,0) M(0,3,1) M(0,3,2) M(0,3,3) \
  M(0,4,0) M(0,4,1) M(0,4,2) M(0,4,3) M(0,5,0) M(0,5,1) M(0,5,2) M(0,5,3) \
  M(0,6,0) M(0,6,1) M(0,6,2) M(0,6,3) M(0,7,0) M(0,7,1) M(0,7,2) M(0,7,3) \
  M(1,0,0) M(1,0,1) M(1,0,2) M(1,0,3) M(1,1,0) M(1,1,1) M(1,1,2) M(1,1,3) \
  M(1,2,0) M(1,2,1) M(1,2,2) M(1,2,3) M(1,3,0) M(1,3,1) M(1,3,2) M(1,3,3) \
  M(1,4,0) M(1,4,1) M(1,4,2) M(1,4,3) M(1,5,0) M(1,5,1) M(1,5,2) M(1,5,3) \
  M(1,6,0) M(1,6,1) M(1,6,2) M(1,6,3) M(1,7,0) M(1,7,1) M(1,7,2) M(1,7,3)
#define LT8(M) \
  M(0, H_0_0_0,H_0_0_1,H_0_0_2,H_0_0_3, H_1_0_0,H_1_0_1,H_1_0_2,H_1_0_3) \
  M(1, H_0_1_0,H_0_1_1,H_0_1_2,H_0_1_3, H_1_1_0,H_1_1_1,H_1_1_2,H_1_1_3) \
  M(2, H_0_2_0,H_0_2_1,H_0_2_2,H_0_2_3, H_1_2_0,H_1_2_1,H_1_2_2,H_1_2_3) \
  M(3, H_0_3_0,H_0_3_1,H_0_3_2,H_0_3_3, H_1_3_0,H_1_3_1,H_1_3_2,H_1_3_3) \
  M(4, H_0_4_0,H_0_4_1,H_0_4_2,H_0_4_3, H_1_4_0,H_1_4_1,H_1_4_2,H_1_4_3) \
  M(5, H_0_5_0,H_0_5_1,H_0_5_2,H_0_5_3, H_1_5_0,H_1_5_1,H_1_5_2,H_1_5_3) \
  M(6, H_0_6_0,H_0_6_1,H_0_6_2,H_0_6_3, H_1_6_0,H_1_6_1,H_1_6_2,H_1_6_3) \
  M(7, H_0_7_0,H_0_7_1,H_0_7_2,H_0_7_3, H_1_7_0,H_1_7_1,H_1_7_2,H_1_7_3)

// ---- weight prep: fp32 W -> hi/lo bf16 A-fragments in d_ws (RNE) ----
__global__ void prep_kernel(const float* __restrict__ rw1,
                            const float* __restrict__ rw2,
                            unsigned short* __restrict__ wsHi,
                            unsigned short* __restrict__ wsLo) {
    int id = blockIdx.x * 256 + threadIdx.x;      // 0 .. 28671
    int lane = id & 63, kc = (id >> 6) & 3, t = (id >> 8) & 7, L = id >> 11;
    int i = L >> 1;
    bool isW1 = ((L & 1) == 0);
    const float* W = (isW1 ? rw1 : rw2) + i * HID * HID;
    float sc = (isW1 && i > 0) ? 0.5f : 1.0f;     // fold wgt1 (ave_first)
    int m = t * 16 + (lane & 15);                  // A row (feat_out)
    int k0 = kc * 32 + (lane >> 4) * 8;            // A col base (feat_in)
    const float* src = W + m * HID + k0;
    int off = id * 8;
    for (int j = 0; j < 8; ++j) {
        float w = src[j] * sc;
        u32 r = rne(__builtin_bit_cast(u32, w));
        float lo = w - __builtin_bit_cast(float, r & 0xffff0000u);
        u32 rl = rne(__builtin_bit_cast(u32, lo));
        wsHi[off + j] = (unsigned short)(r >> 16);
        wsLo[off + j] = (unsigned short)(rl >> 16);
    }
}

__global__ void __launch_bounds__(BT)
__attribute__((amdgpu_waves_per_eu(2)))
siren_mfma(const float* __restrict__ x,
           const float* __restrict__ w0p, const float* __restrict__ b0p,
           const float* __restrict__ b1p, const float* __restrict__ b2p,
           const float* __restrict__ wfp, const float* __restrict__ bfp,
           const u4v* __restrict__ whi, const u4v* __restrict__ wlo,
           float* __restrict__ out, int NP)
{
    __shared__ unsigned short PHI[32 * RSTR];      // hi bf16 plane, 8704 B
    __shared__ unsigned short PLO[32 * RSTR];      // lo bf16 plane, 8704 B

    const int lane = threadIdx.x & 63;
    const int ln = lane & 15, q = lane >> 4;
    const int q4 = q * 4, q8 = q * 8;
    const int base_pt = blockIdx.x * 32;

    // ---- first SineLayer (fp32 VALU) ----
    // H_{nt}_{mt}_{reg} = h[point = 16*nt+ln][feat = 16*mt+q4+reg]
#define LX2(nt) float X_##nt, Y_##nt, Z_##nt; \
    { int p_ = base_pt + nt*16 + ln; int ix_ = p_ < NP ? p_ : NP - 1; \
      X_##nt = x[3*ix_+0]; Y_##nt = x[3*ix_+1]; Z_##nt = x[3*ix_+2]; }
    LX2(0) LX2(1)
#define FL0(nt,mt,reg) float H_##nt##_##mt##_##reg; \
    { const int f_ = mt*16 + q4 + reg; \
      H_##nt##_##mt##_##reg = sin_om(fmaf(w0p[3*f_+0], X_##nt, \
        fmaf(w0p[3*f_+1], Y_##nt, fmaf(w0p[3*f_+2], Z_##nt, b0p[f_])))); }
    LH64(FL0)

    // activation B-fragments (hi/lo), {nt}x{kc}
    s8v BH00, BH01, BH02, BH03, BH10, BH11, BH12, BH13;
    s8v BL00, BL01, BL02, BL03, BL10, BL11, BL12, BL13;

    // h regs -> planes [point][feat]: 4 contiguous feats -> b64 per plane
#define WH(mt, ea0,ea1,ea2,ea3, eb0,eb1,eb2,eb3) { \
    f4v va = {ea0, ea1, ea2, ea3}; \
    f4v vb = {eb0, eb1, eb2, eb3}; \
    plane_store4(PHI, PLO, ln*RSTR + mt*16 + q4, va); \
    plane_store4(PHI, PLO, (16+ln)*RSTR + mt*16 + q4, vb); }

    // B-frags: b128 per plane
#define RF(nt,kc) { const int a_ = (nt*16+ln)*RSTR + kc*32 + q8; \
    BH##nt##kc = *(const s8v*)&PHI[a_]; \
    BL##nt##kc = *(const s8v*)&PLO[a_]; }

    // 4-term split product for one kc chunk into both point-tile accs
#define KCH(BHk0, BLk0, BHk1, BLk1, g_, r_) { \
    s8v ah = __builtin_bit_cast(s8v, g_), al = __builtin_bit_cast(s8v, r_); \
    c0 = mfma16(ah, BHk0, c0); c0 = mfma16(al, BHk0, c0); \
    c0 = mfma16(ah, BLk0, c0); c0 = mfma16(al, BLk0, c0); \
    c1 = mfma16(ah, BHk1, c1); c1 = mfma16(al, BHk1, c1); \
    c1 = mfma16(ah, BLk1, c1); c1 = mfma16(al, BLk1, c1); }

    // matmul1 (transposed): S1^T[feat_out][point] = W1 * h^T; sine; store
#define MM1(mt) { \
    const int fb = (L1*32 + mt*4)*64 + lane; \
    u4v g0 = whi[fb], g1 = whi[fb+64], g2 = whi[fb+128], g3 = whi[fb+192]; \
    u4v r0 = wlo[fb], r1 = wlo[fb+64], r2 = wlo[fb+128], r3 = wlo[fb+192]; \
    f4v c0 = *(const f4v*)(B1l + mt*16 + q4); \
    f4v c1 = c0; \
    KCH(BH00, BL00, BH10, BL10, g0, r0) \
    KCH(BH01, BL01, BH11, BL11, g1, r1) \
    KCH(BH02, BL02, BH12, BL12, g2, r2) \
    KCH(BH03, BL03, BH13, BL13, g3, r3) \
    f4v sa = {sin_om(c0.x), sin_om(c0.y), sin_om(c0.z), sin_om(c0.w)}; \
    f4v sb = {sin_om(c1.x), sin_om(c1.y), sin_om(c1.z), sin_om(c1.w)}; \
    plane_store4(PHI, PLO, ln*RSTR + mt*16 + q4, sa); \
    plane_store4(PHI, PLO, (16+ln)*RSTR + mt*16 + q4, sb); }

    // matmul2 (transposed) + epilogue h = wgt2*(h + sin(s2))
#define ST5(mt, ea0,ea1,ea2,ea3, eb0,eb1,eb2,eb3) { \
    const int fb = (L2*32 + mt*4)*64 + lane; \
    u4v g0 = whi[fb], g1 = whi[fb+64], g2 = whi[fb+128], g3 = whi[fb+192]; \
    u4v r0 = wlo[fb], r1 = wlo[fb+64], r2 = wlo[fb+128], r3 = wlo[fb+192]; \
    f4v c0 = *(const f4v*)(B2l + mt*16 + q4); \
    f4v c1 = c0; \
    KCH(BH00, BL00, BH10, BL10, g0, r0) \
    KCH(BH01, BL01, BH11, BL11, g1, r1) \
    KCH(BH02, BL02, BH12, BL12, g2, r2) \
    KCH(BH03, BL03, BH13, BL13, g3, r3) \
    ea0 = wgt2 * (ea0 + sin_om(c0.x)); \
    ea1 = wgt2 * (ea1 + sin_om(c0.y)); \
    ea2 = wgt2 * (ea2 + sin_om(c0.z)); \
    ea3 = wgt2 * (ea3 + sin_om(c0.w)); \
    eb0 = wgt2 * (eb0 + sin_om(c1.x)); \
    eb1 = wgt2 * (eb1 + sin_om(c1.y)); \
    eb2 = wgt2 * (eb2 + sin_om(c1.z)); \
    eb3 = wgt2 * (eb3 + sin_om(c1.w)); }

    for (int i = 0; i < NRES; ++i) {
        const int L1 = 2 * i, L2 = 2 * i + 1;
        const float* __restrict__ B1l = b1p + i * HID;
        const float* __restrict__ B2l = b2p + i * HID;
        const float wgt2 = (i == NRES - 1) ? 0.5f : 1.0f;   // ave_second

        LT8(WH)         // h regs -> planes (b64 stores)
        LAF8(RF)        // h B-fragments
        LMT8(MM1)       // matmul1 + sine -> planes
        LAF8(RF)        // s1 B-fragments
        LT8(ST5)        // matmul2 + sine + residual epilogue
    }

    // ---- final linear head: out[p] = bf + sum_f wf[f] h[p][f] ----
#define WFV(mt) f4v WF##mt = *(const f4v*)(wfp + mt*16 + q4);
    LMT8(WFV)
    float P_0 = 0.f, P_1 = 0.f;
#define HACC(nt,mt,reg) P_##nt = fmaf(WF##mt[reg], H_##nt##_##mt##_##reg, P_##nt);
    LH64(HACC)
    P_0 += __shfl_xor(P_0, 16); P_0 += __shfl_xor(P_0, 32);
    P_1 += __shfl_xor(P_1, 16); P_1 += __shfl_xor(P_1, 32);
    const float bf0 = bfp[0];
    if (q == 0) {
        int p0 = base_pt + ln, p1 = base_pt + 16 + ln;
        if (p0 < NP) out[p0] = P_0 + bf0;
        if (p1 < NP) out[p1] = P_1 + bf0;
    }
}

extern "C" void kernel_launch(void* const* d_in, const int* in_sizes, int n_in,
                              void* d_out, int out_size, void* d_ws, size_t ws_size,
                              hipStream_t stream) {
    const float* x   = (const float*)d_in[0];
    const float* w0  = (const float*)d_in[1];
    const float* b0  = (const float*)d_in[2];
    const float* rw1 = (const float*)d_in[3];
    const float* rb1 = (const float*)d_in[4];
    const float* rw2 = (const float*)d_in[5];
    const float* rb2 = (const float*)d_in[6];
    const float* wf  = (const float*)d_in[7];
    const float* bf  = (const float*)d_in[8];
    float* out = (float*)d_out;

    unsigned short* wsHi = (unsigned short*)d_ws;          // needs 917504 B
    unsigned short* wsLo = wsHi + FRAG_ELEMS;

    const int n = in_sizes[0] / 3;                          // 200000
    prep_kernel<<<112, 256, 0, stream>>>(rw1, rw2, wsHi, wsLo);
    const int grid = (n + 31) / 32;                         // 6250 waves
    siren_mfma<<<grid, BT, 0, stream>>>(x, w0, b0, rb1, rb2, wf, bf,
                                        (const u4v*)wsHi, (const u4v*)wsLo,
                                        out, n);
}